// Round 6
// baseline (258.441 us; speedup 1.0000x reference)
//
#include <hip/hip_runtime.h>

// LinearAttention: N=8, L=S=4096, H=8, D=M=64, fp32.
// phase1 (16 s-splits, MFMA, cooperative, pipelined): block 256 = 4 waves,
//   38.9 KB LDS -> 4 blocks/CU. K-waves stage phi(K)*mask, V-waves stage V,
//   transposed [64 d][32 s] bf16 hi/lo with ROW STRIDE 72 B (no swizzle:
//   odd-dword stride makes b64 staging writes exactly bank-minimal and b128
//   frag reads near-minimal). Raw s_barrier + lgkmcnt(0) only (NO vmcnt drain
//   in the loop) + two-deep register prefetch: loads for k-step t+2 issued at
//   step t stay in flight across barriers (T3/T4 mechanism). 12 MFMA/step/wave
//   (hi*hi+hi*lo+lo*hi), quadrant acc written straight to KVp.
// reduce: sums 16 split partials; emits KV^T bf16 hi/lo ([m][d]) + fp32 Ksum.
// phase2 (MFMA, unchanged, verified): Q straight from global, bf16 hi/lo
//   split, no LDS, no barriers; denominator exact fp32.

#define SLEN 4096
#define LLEN 4096
#define NHTOT 64      // N*H
#define HD   512      // H*D row stride in elements
#define NSPLIT 16
#define EPSF 1e-6f

#define ROWB 72       // LDS bytes per d-row (64 data + 8 pad)
#define ARRB 4608     // 64 * ROWB  (one hi or lo plane)
#define BUFB 18432    // 4 planes: KThi|KTlo|VThi|VTlo

typedef short s16x8 __attribute__((ext_vector_type(8)));
typedef float f32x4 __attribute__((ext_vector_type(4)));

__device__ __forceinline__ float phi(float x) {
    return x > 0.0f ? x + 1.0f : __expf(x);
}

// pack bf16(hi) of two floats into one u32 (a -> low half = lower s index)
__device__ __forceinline__ unsigned pack_hi2(float a, float b) {
    return (__float_as_uint(a) >> 16) | (__float_as_uint(b) & 0xFFFF0000u);
}
// residual after bf16 truncation (exact)
__device__ __forceinline__ float bres(float x) {
    return x - __uint_as_float(__float_as_uint(x) & 0xFFFF0000u);
}
// scalar split for reduce kernel
__device__ __forceinline__ void bsplit(float x, short& hi, short& lo) {
    const unsigned bx = __float_as_uint(x);
    hi = (short)(bx >> 16);
    const float hf = __uint_as_float(bx & 0xFFFF0000u);
    lo = (short)(__float_as_uint(x - hf) >> 16);
}

// ---------------- Phase 1: per-split KV partials via MFMA ----------------
// grid (NSPLIT=16, 64), block 256 = 4 waves, 38912 B LDS -> 4 blocks/CU.
// Block: 256 s-rows in 8 k-steps of 32. Transposed bf16 tiles:
//   element (d, s) at byte d*72 + (s>>2)*8 + (s&3)*2  (== d*72 + s*2 order).
__global__ __launch_bounds__(256, 4)
void la_phase1(const float* __restrict__ Kg, const float* __restrict__ Vg,
               const float* __restrict__ maskg,
               float* __restrict__ KVp, float* __restrict__ Ksump) {
    __shared__ char  sb[2][BUFB];   // double buffer
    __shared__ float ksb[8 * 64];   // ksum partials (2 KB) -> 38912 B total

    const int tid  = threadIdx.x;
    const int w    = tid >> 6;
    const int lane = tid & 63;
    const int nh   = blockIdx.y;
    const int n    = nh >> 3;
    const int h    = nh & 7;
    const int sp   = blockIdx.x;

    // staging role: waves 0-1 stage K, waves 2-3 stage V.
    // idx in [0,128): c = d-chunk (4 floats), q = s-quad (4 rows), q in 0..7
    const bool isK = (w < 2);
    const int idx  = tid & 127;
    const int c    = idx & 15;
    const int q    = idx >> 4;
    const int c4   = c * 4;
    const float* __restrict__ src = isK ? Kg : Vg;
    const int arro = isK ? 0 : 2 * ARRB;

    // mfma role: wave quadrant (wd, wm); lane r = tile row/col, a = k-octet
    const int wd = w & 1, wm = w >> 1;
    const int r  = lane & 15, a = lane >> 4;

    const size_t base = (size_t)n * SLEN * HD + (size_t)h * 64;
    const float* mrow = maskg + (size_t)n * SLEN;
    const int brow0 = sp * 256;

    f32x4 acc[2][2];
    #pragma unroll
    for (int dt = 0; dt < 2; ++dt)
        #pragma unroll
        for (int mt = 0; mt < 2; ++mt)
            acc[dt][mt] = (f32x4){0.f, 0.f, 0.f, 0.f};
    float4 ksp = make_float4(0.f, 0.f, 0.f, 0.f);

#define LOADSTEP(P, PM, T) do {                                               \
        _Pragma("unroll")                                                     \
        for (int j = 0; j < 4; ++j) {                                         \
            const int s_ = brow0 + (T) * 32 + q * 4 + j;                      \
            P[j] = *(const float4*)(src + base + (size_t)s_ * HD + c4);       \
            if (isK) PM[j] = mrow[s_];                                        \
        }                                                                     \
    } while (0)

#define STAGESTEP(P, PM, BUF) do {                                            \
        char* bb_ = &sb[BUF][arro];                                           \
        float4 vv_[4];                                                        \
        if (isK) {                                                            \
            _Pragma("unroll")                                                 \
            for (int j = 0; j < 4; ++j) {                                     \
                float4 kq_ = P[j];                                            \
                const float mm_ = PM[j];                                      \
                kq_.x = phi(kq_.x) * mm_; kq_.y = phi(kq_.y) * mm_;           \
                kq_.z = phi(kq_.z) * mm_; kq_.w = phi(kq_.w) * mm_;           \
                ksp.x += kq_.x; ksp.y += kq_.y;                               \
                ksp.z += kq_.z; ksp.w += kq_.w;                               \
                vv_[j] = kq_;                                                 \
            }                                                                 \
        } else {                                                              \
            _Pragma("unroll")                                                 \
            for (int j = 0; j < 4; ++j) vv_[j] = P[j];                        \
        }                                                                     \
        _Pragma("unroll")                                                     \
        for (int i = 0; i < 4; ++i) {                                         \
            const int off_ = (c4 + i) * ROWB + q * 8;                         \
            const float x0_ = (&vv_[0].x)[i], x1_ = (&vv_[1].x)[i];           \
            const float x2_ = (&vv_[2].x)[i], x3_ = (&vv_[3].x)[i];           \
            *(uint2*)(bb_ + off_) =                                           \
                make_uint2(pack_hi2(x0_, x1_), pack_hi2(x2_, x3_));           \
            *(uint2*)(bb_ + ARRB + off_) =                                    \
                make_uint2(pack_hi2(bres(x0_), bres(x1_)),                    \
                           pack_hi2(bres(x2_), bres(x3_)));                   \
        }                                                                     \
    } while (0)

    // raw barrier: LDS-visibility only (lgkmcnt 0), NO vmcnt drain ->
    // 2-deep global prefetch stays in flight across k-steps.
#define PIPE_BAR() do {                                                       \
        asm volatile("s_waitcnt lgkmcnt(0)" ::: "memory");                    \
        __builtin_amdgcn_s_barrier();                                         \
        asm volatile("" ::: "memory");                                        \
    } while (0)

#define COMPSTEP(BUF) do {                                                    \
        const char* rbK_ = &sb[BUF][0];                                       \
        const char* rbV_ = &sb[BUF][2 * ARRB];                                \
        s16x8 Ah_[2], Al_[2], Bh_[2], Bl_[2];                                 \
        _Pragma("unroll")                                                     \
        for (int dt = 0; dt < 2; ++dt) {                                      \
            const int off_ = ((wd * 2 + dt) * 16 + r) * ROWB + a * 16;        \
            Ah_[dt] = *(const s16x8*)(rbK_ + off_);                           \
            Al_[dt] = *(const s16x8*)(rbK_ + ARRB + off_);                    \
        }                                                                     \
        _Pragma("unroll")                                                     \
        for (int mt = 0; mt < 2; ++mt) {                                      \
            const int off_ = ((wm * 2 + mt) * 16 + r) * ROWB + a * 16;        \
            Bh_[mt] = *(const s16x8*)(rbV_ + off_);                           \
            Bl_[mt] = *(const s16x8*)(rbV_ + ARRB + off_);                    \
        }                                                                     \
        _Pragma("unroll")                                                     \
        for (int dt = 0; dt < 2; ++dt)                                        \
            _Pragma("unroll")                                                 \
            for (int mt = 0; mt < 2; ++mt) {                                  \
                acc[dt][mt] = __builtin_amdgcn_mfma_f32_16x16x32_bf16(        \
                    Ah_[dt], Bh_[mt], acc[dt][mt], 0, 0, 0);                  \
                acc[dt][mt] = __builtin_amdgcn_mfma_f32_16x16x32_bf16(        \
                    Ah_[dt], Bl_[mt], acc[dt][mt], 0, 0, 0);                  \
                acc[dt][mt] = __builtin_amdgcn_mfma_f32_16x16x32_bf16(        \
                    Al_[dt], Bh_[mt], acc[dt][mt], 0, 0, 0);                  \
            }                                                                 \
    } while (0)

    // two-deep prologue: pe holds step 0, po holds step 1 (in flight)
    float4 pe[4], po[4];
    float  pme[4], pmo[4];
    LOADSTEP(pe, pme, 0);
    LOADSTEP(po, pmo, 1);

    #pragma unroll
    for (int tt = 0; tt < 4; ++tt) {
        // even k-step 2*tt -> buffer 0
        STAGESTEP(pe, pme, 0);
        PIPE_BAR();
        if (tt < 3) LOADSTEP(pe, pme, 2 * tt + 2);   // issue t+2, in flight over 2 bodies
        COMPSTEP(0);
        // odd k-step 2*tt+1 -> buffer 1
        STAGESTEP(po, pmo, 1);
        PIPE_BAR();
        if (tt < 3) LOADSTEP(po, pmo, 2 * tt + 3);
        COMPSTEP(1);
    }

    // ---- ksum block reduce ----
    if (isK) *(float4*)&ksb[q * 64 + c4] = ksp;
    __syncthreads();
    if (tid < 64) {
        float ssum = 0.f;
        #pragma unroll
        for (int rr = 0; rr < 8; ++rr) ssum += ksb[rr * 64 + tid];
        Ksump[((size_t)sp * NHTOT + nh) * 64 + tid] = ssum;
    }

    // ---- direct global write of this wave's disjoint 32x32 quadrant ----
    // D layout: col = r (m within tile), row = a*4 + pp (d within tile)
    float* outp = KVp + ((size_t)sp * NHTOT + nh) * 4096;
    #pragma unroll
    for (int dt = 0; dt < 2; ++dt)
        #pragma unroll
        for (int mt = 0; mt < 2; ++mt)
            #pragma unroll
            for (int pp = 0; pp < 4; ++pp)
                outp[(wd * 32 + dt * 16 + a * 4 + pp) * 64 + wm * 32 + mt * 16 + r] = acc[dt][mt][pp];

#undef LOADSTEP
#undef STAGESTEP
#undef PIPE_BAR
#undef COMPSTEP
}

// ---------------- Reduce + transpose + bf16 split ----------------
// grid (4, 64): block handles m-range [bx*16, bx*16+16) of one nh.
__global__ __launch_bounds__(256)
void la_reduce(const float* __restrict__ KVp, const float* __restrict__ Ksump,
               short* __restrict__ KVThi, short* __restrict__ KVTlo,
               float* __restrict__ Ksum) {
    __shared__ float ld[64 * 20];   // [64 d][16 m], stride 20

    const int nh  = blockIdx.y;
    const int mb  = blockIdx.x * 16;
    const int tid = threadIdx.x;

    const int d    = tid >> 2;
    const int moff = (tid & 3) * 4;
    float4 a = make_float4(0.f, 0.f, 0.f, 0.f);
    #pragma unroll
    for (int s = 0; s < NSPLIT; ++s) {
        const float4 v = *(const float4*)&KVp[((size_t)s * NHTOT + nh) * 4096 + d * 64 + mb + moff];
        a.x += v.x; a.y += v.y; a.z += v.z; a.w += v.w;
    }
    *(float4*)&ld[d * 20 + moff] = a;
    __syncthreads();

    const int mloc = tid >> 4;
    const int d0   = (tid & 15) * 4;
    short hi4[4], lo4[4];
    #pragma unroll
    for (int i = 0; i < 4; ++i)
        bsplit(ld[(d0 + i) * 20 + mloc], hi4[i], lo4[i]);
    const size_t o = (size_t)nh * 4096 + (mb + mloc) * 64 + d0;
    *(short4*)&KVThi[o] = *(short4*)hi4;
    *(short4*)&KVTlo[o] = *(short4*)lo4;

    if (blockIdx.x == 0 && tid < 64) {
        float b = 0.f;
        #pragma unroll
        for (int s = 0; s < NSPLIT; ++s)
            b += Ksump[((size_t)s * NHTOT + nh) * 64 + tid];
        Ksum[nh * 64 + tid] = b;
    }
}

// ---------------- Phase 2: MFMA out = phi(Q) @ KV, normalized ----------------
// (unchanged - verified)
__global__ __launch_bounds__(256)
void la_phase2(const float* __restrict__ Qg,
               const short* __restrict__ KVThi, const short* __restrict__ KVTlo,
               const float* __restrict__ Ksum, float* __restrict__ Og) {
    const int tid  = threadIdx.x;
    const int w    = tid >> 6;
    const int lane = tid & 63;
    const int nh   = blockIdx.y;
    const int n    = nh >> 3;
    const int h    = nh & 7;
    const int l0   = blockIdx.x * 128 + w * 32;

    const int r  = lane & 15;
    const int g4 = lane >> 4;

    const short* bhp = KVThi + (size_t)nh * 4096;
    const short* blp = KVTlo + (size_t)nh * 4096;
    const float* ksp = Ksum + nh * 64;

    f32x4 acc[2][4];
    #pragma unroll
    for (int t = 0; t < 2; ++t)
        #pragma unroll
        for (int u = 0; u < 4; ++u)
            acc[t][u] = (f32x4){0.f, 0.f, 0.f, 0.f};
    float den[2] = {0.f, 0.f};

    #pragma unroll
    for (int g = 0; g < 2; ++g) {
        const int db = g * 32 + g4 * 8;

        s16x8 Bh[4], Bl[4];
        #pragma unroll
        for (int u = 0; u < 4; ++u) {
            Bh[u] = *(const s16x8*)&bhp[(u * 16 + r) * 64 + db];
            Bl[u] = *(const s16x8*)&blp[(u * 16 + r) * 64 + db];
        }
        const float4 k0 = *(const float4*)&ksp[db];
        const float4 k1 = *(const float4*)&ksp[db + 4];

        #pragma unroll
        for (int t = 0; t < 2; ++t) {
            const float* qrow = Qg + ((size_t)(n * LLEN + l0 + t * 16 + r) * 8 + h) * 64 + db;
            float4 q0 = *(const float4*)qrow;
            float4 q1 = *(const float4*)(qrow + 4);
            q0.x = phi(q0.x); q0.y = phi(q0.y); q0.z = phi(q0.z); q0.w = phi(q0.w);
            q1.x = phi(q1.x); q1.y = phi(q1.y); q1.z = phi(q1.z); q1.w = phi(q1.w);

            float dn = den[t];
            dn = fmaf(q0.x, k0.x, dn); dn = fmaf(q0.y, k0.y, dn);
            dn = fmaf(q0.z, k0.z, dn); dn = fmaf(q0.w, k0.w, dn);
            dn = fmaf(q1.x, k1.x, dn); dn = fmaf(q1.y, k1.y, dn);
            dn = fmaf(q1.z, k1.z, dn); dn = fmaf(q1.w, k1.w, dn);
            den[t] = dn;

            s16x8 Ah, Al;
            {
                short hh, ll;
                bsplit(q0.x, hh, ll); Ah[0] = hh; Al[0] = ll;
                bsplit(q0.y, hh, ll); Ah[1] = hh; Al[1] = ll;
                bsplit(q0.z, hh, ll); Ah[2] = hh; Al[2] = ll;
                bsplit(q0.w, hh, ll); Ah[3] = hh; Al[3] = ll;
                bsplit(q1.x, hh, ll); Ah[4] = hh; Al[4] = ll;
                bsplit(q1.y, hh, ll); Ah[5] = hh; Al[5] = ll;
                bsplit(q1.z, hh, ll); Ah[6] = hh; Al[6] = ll;
                bsplit(q1.w, hh, ll); Ah[7] = hh; Al[7] = ll;
            }
            #pragma unroll
            for (int u = 0; u < 4; ++u) {
                acc[t][u] = __builtin_amdgcn_mfma_f32_16x16x32_bf16(Ah, Bh[u], acc[t][u], 0, 0, 0);
                acc[t][u] = __builtin_amdgcn_mfma_f32_16x16x32_bf16(Ah, Bl[u], acc[t][u], 0, 0, 0);
                acc[t][u] = __builtin_amdgcn_mfma_f32_16x16x32_bf16(Al, Bh[u], acc[t][u], 0, 0, 0);
            }
        }
    }

    #pragma unroll
    for (int t = 0; t < 2; ++t) {
        den[t] += __shfl_xor(den[t], 16, 64);
        den[t] += __shfl_xor(den[t], 32, 64);
    }

    #pragma unroll
    for (int t = 0; t < 2; ++t) {
        #pragma unroll
        for (int k = 0; k < 4; ++k) {
            const int ro = g4 * 4 + k;
            const float dk = __shfl(den[t], ro, 64);
            const float z  = 1.0f / (dk + EPSF);
            const int l = l0 + t * 16 + ro;
            float* op = &Og[((size_t)(n * LLEN + l) * 8 + h) * 64 + r];
            #pragma unroll
            for (int u = 0; u < 4; ++u)
                op[u * 16] = acc[t][u][k] * z;
        }
    }
}

extern "C" void kernel_launch(void* const* d_in, const int* in_sizes, int n_in,
                              void* d_out, int out_size, void* d_ws, size_t ws_size,
                              hipStream_t stream) {
    const float* Q    = (const float*)d_in[0];
    const float* K    = (const float*)d_in[1];
    const float* V    = (const float*)d_in[2];
    const float* mask = (const float*)d_in[3];
    float* out = (float*)d_out;

    float* KVp   = (float*)d_ws;                              // [16][64][4096] f32 = 16 MB
    float* Ksump = KVp + (size_t)NSPLIT * NHTOT * 4096;       // [16][64][64]
    float* Ksum  = Ksump + (size_t)NSPLIT * NHTOT * 64;       // [64][64] f32
    short* KVThi = (short*)(Ksum + NHTOT * 64);               // [64][64m][64d] bf16
    short* KVTlo = KVThi + (size_t)NHTOT * 4096;
    // every ws element read is written first (no memset needed)

    dim3 g1(NSPLIT, NHTOT);
    la_phase1<<<g1, 256, 0, stream>>>(K, V, mask, KVp, Ksump);

    dim3 gr(4, NHTOT);
    la_reduce<<<gr, 256, 0, stream>>>(KVp, Ksump, KVThi, KVTlo, Ksum);

    dim3 g2(LLEN / 128, NHTOT);
    la_phase2<<<g2, 256, 0, stream>>>(Q, KVThi, KVTlo, Ksum, out);
}